// Round 7
// baseline (252.464 us; speedup 1.0000x reference)
//
#include <hip/hip_runtime.h>
#include <hip/hip_bf16.h>
#include <stdint.h>
#include <stddef.h>

#define N_TOT 1024
#define M_TOT 50000
#define M_PAD 50176   // 392 * 128 = 8 XCDs * 49 tiles * 128
#define MT_TILES 392
#define D_TOT 512
#define NC    10

typedef __attribute__((ext_vector_type(8))) __bf16 bf16x8;
typedef __attribute__((ext_vector_type(4))) float f32x4;
typedef __attribute__((ext_vector_type(4))) unsigned int u32x4;

union Frag16 { u32x4 q; bf16x8 b; unsigned short u[8]; };
union Pack8  { u32x4 q; unsigned short u[8]; };

__device__ __forceinline__ unsigned short f2bf(float x) {
  unsigned int u = __float_as_uint(x);
  unsigned int r = (u + 0x7fffu + ((u >> 16) & 1u)) >> 16;
  return (unsigned short)r;
}

__device__ __forceinline__ void gld_lds16(const void* g, void* l) {
  auto gp = (__attribute__((address_space(1))) unsigned int*)(uintptr_t)g;
  auto lp = (__attribute__((address_space(3))) unsigned int*)(uintptr_t)l;
  __builtin_amdgcn_global_load_lds(gp, lp, 16, 0, 0);
}

// Convert exemplars -> bf16 (plain), x -> bf16(x * Sigma_inv); compute
// e_sq[m] = sum S*e^2, x_sq[n] = sum S*x^2. One wave per row (512 elems, 8/lane).
// Also zeroes logits (folded former zero_f32 launch).
__global__ void prep_rows(const float* __restrict__ e, const float* __restrict__ x,
                          const float* __restrict__ S,
                          unsigned short* __restrict__ eb, unsigned short* __restrict__ xb,
                          float* __restrict__ e_sq, float* __restrict__ x_sq,
                          float* __restrict__ logits) {
  if (blockIdx.x < (N_TOT * NC + 255) / 256) {
    const int i = blockIdx.x * 256 + threadIdx.x;
    if (i < N_TOT * NC) logits[i] = 0.f;
  }

  const int lane = threadIdx.x & 63;
  const int wid  = threadIdx.x >> 6;
  const int row  = blockIdx.x * 4 + wid;   // 0 .. 51199
  const int d0   = lane * 8;

  float4 s0 = *(const float4*)(S + d0);
  float4 s1 = *(const float4*)(S + d0 + 4);
  float ss[8] = {s0.x, s0.y, s0.z, s0.w, s1.x, s1.y, s1.z, s1.w};

  float acc = 0.f;
  Pack8 o;

  if (row < M_PAD) {
    if (row < M_TOT) {
      const float* src = e + (size_t)row * D_TOT + d0;
      float4 v0 = *(const float4*)src;
      float4 v1 = *(const float4*)(src + 4);
      float vv[8] = {v0.x, v0.y, v0.z, v0.w, v1.x, v1.y, v1.z, v1.w};
      #pragma unroll
      for (int j = 0; j < 8; ++j) { acc += ss[j] * vv[j] * vv[j]; o.u[j] = f2bf(vv[j]); }
    } else {
      #pragma unroll
      for (int j = 0; j < 8; ++j) o.u[j] = 0;
      acc = 0.f;
    }
    *(u32x4*)(eb + (size_t)row * D_TOT + d0) = o.q;
    #pragma unroll
    for (int off = 32; off; off >>= 1) acc += __shfl_down(acc, off);
    if (lane == 0) e_sq[row] = (row < M_TOT) ? acc : 1e30f;  // pad rows: exp(-1e30)=0
  } else {
    const int xr = row - M_PAD;  // 0..1023
    const float* src = x + (size_t)xr * D_TOT + d0;
    float4 v0 = *(const float4*)src;
    float4 v1 = *(const float4*)(src + 4);
    float vv[8] = {v0.x, v0.y, v0.z, v0.w, v1.x, v1.y, v1.z, v1.w};
    #pragma unroll
    for (int j = 0; j < 8; ++j) {
      float w = ss[j] * vv[j];
      acc += w * vv[j];             // S * x^2
      o.u[j] = f2bf(w);             // bf16(x * S)
    }
    *(u32x4*)(xb + (size_t)xr * D_TOT + d0) = o.q;
    #pragma unroll
    for (int off = 32; off; off >>= 1) acc += __shfl_down(acc, off);
    if (lane == 0) x_sq[xr] = acc;
  }
}

// 128x128 tile, 4 waves (2x2), 16x16x32 bf16 MFMA, K=512 in 16 steps of 32.
// v3: (a) XCD-grouped block decode — blocks with bid%8==c (same XCD under
// round-robin) cover mt in [c*49, c*49+48], all 8 nt back-to-back, so each
// eb panel is fetched into exactly one XCD-L2; (b) 3-deep LDS prefetch with
// counted vmcnt(8) — ~2 compute phases for loads to land.
__launch_bounds__(256)
__global__ void gemm_fused(const unsigned short* __restrict__ xb,
                           const unsigned short* __restrict__ eb,
                           const float* __restrict__ x_sq, const float* __restrict__ e_sq,
                           const int* __restrict__ labels,
                           const float* __restrict__ betap,
                           float* __restrict__ logits) {
  __shared__ unsigned short As[3][128 * 32];  // 3 x 8 KB
  __shared__ unsigned short Bs[3][128 * 32];  // 3 x 8 KB
  __shared__ float cls[128 * NC];             // 5 KB   -> 53 KB total, 3 blk/CU

  const int tid  = threadIdx.x;
  const int lane = tid & 63;
  const int wid  = tid >> 6;
  const int wr   = wid >> 1, wc = wid & 1;   // 2x2 waves, each owns 64x64

  // XCD-aware decode: 3136 blocks = 8 xcd-groups x 392 (49 mt x 8 nt).
  const int bid = blockIdx.x;
  const int c   = bid & 7;       // ~XCD id under round-robin dispatch
  const int k_  = bid >> 3;      // 0..391 within XCD
  const int mt  = c * 49 + (k_ >> 3);   // 0..391, contiguous per XCD
  const int nt  = k_ & 7;               // 8 nt siblings consecutive on one XCD

  // Staging: 512 16B-chunks per tile; chunk cc -> (row=cc>>2, u=cc&3).
  const int cA0 = wid * 128 + lane;
  const int cA1 = cA0 + 64;
  const unsigned short* gA0 = xb + (size_t)(nt * 128 + (cA0 >> 2)) * D_TOT + (cA0 & 3) * 8;
  const unsigned short* gA1 = xb + (size_t)(nt * 128 + (cA1 >> 2)) * D_TOT + (cA1 & 3) * 8;
  const unsigned short* gB0 = eb + (size_t)(mt * 128 + (cA0 >> 2)) * D_TOT + (cA0 & 3) * 8;
  const unsigned short* gB1 = eb + (size_t)(mt * 128 + (cA1 >> 2)) * D_TOT + (cA1 & 3) * 8;

  const f32x4 vzero = {0.f, 0.f, 0.f, 0.f};
  f32x4 acc[4][4];
  #pragma unroll
  for (int i = 0; i < 4; ++i)
    #pragma unroll
    for (int j = 0; j < 4; ++j) acc[i][j] = vzero;

  const int arow = wr * 64 + (lane & 15);
  const int brow = wc * 64 + (lane & 15);
  const int koff = (lane >> 4) * 8;

  // macro params BUF/K0 (a param named 'b' would capture fa[i].b).
  #define STAGE(BUF, K0)                                    \
    do {                                                    \
      gld_lds16(gA0 + (K0), &As[(BUF)][cA0 * 8]);           \
      gld_lds16(gA1 + (K0), &As[(BUF)][cA1 * 8]);           \
      gld_lds16(gB0 + (K0), &Bs[(BUF)][cA0 * 8]);           \
      gld_lds16(gB1 + (K0), &Bs[(BUF)][cA1 * 8]);           \
    } while (0)

  #define COMPUTE(BUF)                                                            \
    do {                                                                          \
      Frag16 fa[4], fb[4];                                                        \
      _Pragma("unroll")                                                           \
      for (int i = 0; i < 4; ++i)                                                 \
        fa[i].q = *(const u32x4*)(&As[(BUF)][(arow + i * 16) * 32 + koff]);       \
      _Pragma("unroll")                                                           \
      for (int j = 0; j < 4; ++j)                                                 \
        fb[j].q = *(const u32x4*)(&Bs[(BUF)][(brow + j * 16) * 32 + koff]);       \
      _Pragma("unroll")                                                           \
      for (int i = 0; i < 4; ++i)                                                 \
        _Pragma("unroll")                                                         \
        for (int j = 0; j < 4; ++j)                                               \
          acc[i][j] = __builtin_amdgcn_mfma_f32_16x16x32_bf16(fa[i].b, fb[j].b,   \
                                                              acc[i][j], 0, 0, 0);\
    } while (0)

  // ---- pipelined K-loop: 16 steps of BK=32, 3-deep prefetch ----
  STAGE(0, 0);
  STAGE(1, 32);
  #pragma unroll
  for (int ks = 0; ks < 14; ++ks) {
    const int nb = (ks + 2) % 3;
    const int cb = ks % 3;
    STAGE(nb, (ks + 2) * 32);                            // prefetch 2 ahead
    asm volatile("s_waitcnt vmcnt(8)" ::: "memory");     // stage(ks) landed (mine)
    __builtin_amdgcn_s_barrier();                        // everyone's landed
    asm volatile("" ::: "memory");
    COMPUTE(cb);
    asm volatile("s_waitcnt lgkmcnt(0)" ::: "memory");   // my ds_reads done
    __builtin_amdgcn_sched_barrier(0);
    __builtin_amdgcn_s_barrier();                        // safe to overwrite buf
  }
  asm volatile("s_waitcnt vmcnt(4)" ::: "memory");       // stage(14) landed
  __builtin_amdgcn_s_barrier();
  asm volatile("" ::: "memory");
  COMPUTE(2);                                            // ks=14 -> buf 2
  asm volatile("s_waitcnt vmcnt(0)" ::: "memory");       // stage(15) landed
  __builtin_amdgcn_s_barrier();
  asm volatile("" ::: "memory");
  COMPUTE(0);                                            // ks=15 -> buf 0
  #undef STAGE
  #undef COMPUTE

  // ---- epilogue ----
  __syncthreads();
  for (int t = tid; t < 128 * NC; t += 256) cls[t] = 0.f;
  __syncthreads();

  const float beta = betap[0];
  const int mbase = mt * 128 + wc * 64 + (lane & 15);
  int   lab[4]; float esq[4]; bool mv[4];
  #pragma unroll
  for (int j = 0; j < 4; ++j) {
    const int m = mbase + j * 16;
    mv[j]  = (m < M_TOT);
    esq[j] = e_sq[m];
    lab[j] = mv[j] ? labels[m] : 0;
  }

  #pragma unroll
  for (int i = 0; i < 4; ++i) {
    #pragma unroll
    for (int r = 0; r < 4; ++r) {
      const int nloc = wr * 64 + i * 16 + (lane >> 4) * 4 + r;  // C: row=(lane>>4)*4+reg
      const float xs = x_sq[nt * 128 + nloc];
      #pragma unroll
      for (int j = 0; j < 4; ++j) {
        if (!mv[j]) continue;
        const float dist = xs + esq[j] - 2.0f * acc[i][j][r];
        const float a = __expf(-beta * dist);
        if (a != 0.0f) atomicAdd(&cls[nloc * NC + lab[j]], a);  // adding 0 is identity
      }
    }
  }
  __syncthreads();
  for (int t = tid; t < 128 * NC; t += 256) {
    const float v = cls[t];
    if (v != 0.0f) atomicAdd(&logits[(size_t)(nt * 128 + (t / NC)) * NC + (t % NC)], v);
  }
}

// Output dtype is FLOAT32 (reference returns f32 softmax) — write float*.
__global__ void softmax_out(const float* __restrict__ logits,
                            const float* __restrict__ gammap,
                            float* __restrict__ out) {
  const int n = blockIdx.x * blockDim.x + threadIdx.x;
  if (n >= N_TOT) return;
  const float g = gammap[0];
  float v[NC], mx = -3.4e38f;
  #pragma unroll
  for (int c = 0; c < NC; ++c) { v[c] = g * logits[n * NC + c]; mx = fmaxf(mx, v[c]); }
  float s = 0.f;
  #pragma unroll
  for (int c = 0; c < NC; ++c) { v[c] = __expf(v[c] - mx); s += v[c]; }
  const float inv = 1.0f / s;
  #pragma unroll
  for (int c = 0; c < NC; ++c) out[n * NC + c] = v[c] * inv;
}

extern "C" void kernel_launch(void* const* d_in, const int* in_sizes, int n_in,
                              void* d_out, int out_size, void* d_ws, size_t ws_size,
                              hipStream_t stream) {
  const float* x      = (const float*)d_in[0];
  const float* e      = (const float*)d_in[1];
  const int*   labels = (const int*)d_in[2];
  const float* S      = (const float*)d_in[3];
  const float* beta   = (const float*)d_in[4];
  const float* gamma  = (const float*)d_in[5];

  char* ws = (char*)d_ws;
  unsigned short* eb     = (unsigned short*)(ws);              // 50176*512*2 = 51,380,224
  unsigned short* xb     = (unsigned short*)(ws + 51380224);   // 1024*512*2  =  1,048,576
  float*          e_sq   = (float*)(ws + 52428800);            // 50176*4     =    200,704
  float*          x_sq   = (float*)(ws + 52629504);            // 1024*4      =      4,096
  float*          logits = (float*)(ws + 52633600);            // 1024*10*4   =     40,960
  // total ws use: 52,674,560 bytes (~50.2 MiB)

  hipLaunchKernelGGL(prep_rows, dim3((M_PAD + N_TOT) / 4), dim3(256), 0, stream,
                     e, x, S, eb, xb, e_sq, x_sq, logits);
  hipLaunchKernelGGL(gemm_fused, dim3(8 * MT_TILES), dim3(256), 0, stream,
                     xb, eb, x_sq, e_sq, labels, beta, logits);
  hipLaunchKernelGGL(softmax_out, dim3(4), dim3(256), 0, stream,
                     logits, gamma, (float*)d_out);
}

// Round 8
// 233.455 us; speedup vs baseline: 1.0814x; 1.0814x over previous
//
#include <hip/hip_runtime.h>
#include <hip/hip_bf16.h>
#include <stdint.h>
#include <stddef.h>

#define N_TOT 1024
#define M_TOT 50000
#define M_PAD 50176   // 196 tiles * 256 rows
#define MT_TILES 196
#define D_TOT 512
#define NC    10

typedef __attribute__((ext_vector_type(8))) __bf16 bf16x8;
typedef __attribute__((ext_vector_type(4))) float f32x4;
typedef __attribute__((ext_vector_type(4))) unsigned int u32x4;

union Frag16 { u32x4 q; bf16x8 b; unsigned short u[8]; };
union Pack8  { u32x4 q; unsigned short u[8]; };

__device__ __forceinline__ unsigned short f2bf(float x) {
  unsigned int u = __float_as_uint(x);
  unsigned int r = (u + 0x7fffu + ((u >> 16) & 1u)) >> 16;
  return (unsigned short)r;
}

__device__ __forceinline__ void gld_lds16(const void* g, void* l) {
  auto gp = (__attribute__((address_space(1))) unsigned int*)(uintptr_t)g;
  auto lp = (__attribute__((address_space(3))) unsigned int*)(uintptr_t)l;
  __builtin_amdgcn_global_load_lds(gp, lp, 16, 0, 0);
}

// Convert exemplars -> bf16 (plain), x -> bf16(x * Sigma_inv); compute
// e_sq[m] = sum S*e^2, x_sq[n] = sum S*x^2. One wave per row. Zeroes logits.
__global__ void prep_rows(const float* __restrict__ e, const float* __restrict__ x,
                          const float* __restrict__ S,
                          unsigned short* __restrict__ eb, unsigned short* __restrict__ xb,
                          float* __restrict__ e_sq, float* __restrict__ x_sq,
                          float* __restrict__ logits) {
  if (blockIdx.x < (N_TOT * NC + 255) / 256) {
    const int i = blockIdx.x * 256 + threadIdx.x;
    if (i < N_TOT * NC) logits[i] = 0.f;
  }

  const int lane = threadIdx.x & 63;
  const int wid  = threadIdx.x >> 6;
  const int row  = blockIdx.x * 4 + wid;   // 0 .. 51199
  const int d0   = lane * 8;

  float4 s0 = *(const float4*)(S + d0);
  float4 s1 = *(const float4*)(S + d0 + 4);
  float ss[8] = {s0.x, s0.y, s0.z, s0.w, s1.x, s1.y, s1.z, s1.w};

  float acc = 0.f;
  Pack8 o;

  if (row < M_PAD) {
    if (row < M_TOT) {
      const float* src = e + (size_t)row * D_TOT + d0;
      float4 v0 = *(const float4*)src;
      float4 v1 = *(const float4*)(src + 4);
      float vv[8] = {v0.x, v0.y, v0.z, v0.w, v1.x, v1.y, v1.z, v1.w};
      #pragma unroll
      for (int j = 0; j < 8; ++j) { acc += ss[j] * vv[j] * vv[j]; o.u[j] = f2bf(vv[j]); }
    } else {
      #pragma unroll
      for (int j = 0; j < 8; ++j) o.u[j] = 0;
      acc = 0.f;
    }
    *(u32x4*)(eb + (size_t)row * D_TOT + d0) = o.q;
    #pragma unroll
    for (int off = 32; off; off >>= 1) acc += __shfl_down(acc, off);
    if (lane == 0) e_sq[row] = (row < M_TOT) ? acc : 1e30f;  // pad rows: exp(-1e30)=0
  } else {
    const int xr = row - M_PAD;  // 0..1023
    const float* src = x + (size_t)xr * D_TOT + d0;
    float4 v0 = *(const float4*)src;
    float4 v1 = *(const float4*)(src + 4);
    float vv[8] = {v0.x, v0.y, v0.z, v0.w, v1.x, v1.y, v1.z, v1.w};
    #pragma unroll
    for (int j = 0; j < 8; ++j) {
      float w = ss[j] * vv[j];
      acc += w * vv[j];             // S * x^2
      o.u[j] = f2bf(w);             // bf16(x * S)
    }
    *(u32x4*)(xb + (size_t)xr * D_TOT + d0) = o.q;
    #pragma unroll
    for (int off = 32; off; off >>= 1) acc += __shfl_down(acc, off);
    if (lane == 0) x_sq[xr] = acc;
  }
}

// v4: BM=256 (e) x BN=128 (x), BK=32, 512 threads / 8 waves (4e x 2x).
// 2-buf prefetch, uniform 3 gld_lds/wave/step, counted vmcnt(3).
// cls aliases As[0] (epilogue-only) -> static LDS 48 KB -> 3 blocks/CU LDS-wise.
// XCD-grouped decode: XCD c gets 196 contiguous (mt-major) work items.
__launch_bounds__(512, 4)
__global__ void gemm_fused(const unsigned short* __restrict__ xb,
                           const unsigned short* __restrict__ eb,
                           const float* __restrict__ x_sq, const float* __restrict__ e_sq,
                           const int* __restrict__ labels,
                           const float* __restrict__ betap,
                           float* __restrict__ logits) {
  __shared__ unsigned short As[2][128 * 32];  // 2 x 8 KB  (x tile)
  __shared__ unsigned short Bs[2][256 * 32];  // 2 x 16 KB (e tile)
  float* cls = (float*)&As[0][0];             // 5 KB, reused AFTER the K-loop

  const int tid  = threadIdx.x;
  const int lane = tid & 63;
  const int wid  = tid >> 6;
  const int we   = wid >> 1;                 // 0..3  e-direction (64 rows each)
  const int wx   = wid & 1;                  // 0..1  x-direction (64 rows each)

  // XCD-grouped decode: 1568 blocks = 8 XCDs x 196; round-robin puts
  // bid%8 on one XCD; give it contiguous mt-major indices.
  const int bid = blockIdx.x;
  const int g   = (bid & 7) * MT_TILES + (bid >> 3);  // [0,1568) bijective
  const int mt  = g >> 3;                             // 0..195
  const int nt  = g & 7;                              // 0..7

  // Staging (per K-step, BK=32): A = 512 chunks of 16B, B = 1024 chunks.
  // Every wave: 1 A-instr + 2 B-instr (uniform -> uniform vmcnt).
  const int cA  = wid * 64 + lane;           // [0,512)
  const int cB0 = wid * 128 + lane;          // [0,1024)
  const int cB1 = cB0 + 64;
  const unsigned short* gA  = xb + (size_t)(nt * 128 + (cA  >> 2)) * D_TOT + (cA  & 3) * 8;
  const unsigned short* gB0 = eb + (size_t)(mt * 256 + (cB0 >> 2)) * D_TOT + (cB0 & 3) * 8;
  const unsigned short* gB1 = eb + (size_t)(mt * 256 + (cB1 >> 2)) * D_TOT + (cB1 & 3) * 8;

  const f32x4 vzero = {0.f, 0.f, 0.f, 0.f};
  f32x4 acc[4][4];
  #pragma unroll
  for (int i = 0; i < 4; ++i)
    #pragma unroll
    for (int j = 0; j < 4; ++j) acc[i][j] = vzero;

  const int arow = wx * 64 + (lane & 15);    // x-row base in As
  const int brow = we * 64 + (lane & 15);    // e-row base in Bs
  const int koff = (lane >> 4) * 8;

  // macro params BUF/K0 (a param named 'b' would capture fa[i].b).
  #define STAGE(BUF, K0)                                    \
    do {                                                    \
      gld_lds16(gA  + (K0), &As[(BUF)][cA  * 8]);           \
      gld_lds16(gB0 + (K0), &Bs[(BUF)][cB0 * 8]);           \
      gld_lds16(gB1 + (K0), &Bs[(BUF)][cB1 * 8]);           \
    } while (0)

  #define COMPUTE(BUF)                                                            \
    do {                                                                          \
      Frag16 fa[4], fb[4];                                                        \
      _Pragma("unroll")                                                           \
      for (int i = 0; i < 4; ++i)                                                 \
        fa[i].q = *(const u32x4*)(&As[(BUF)][(arow + i * 16) * 32 + koff]);       \
      _Pragma("unroll")                                                           \
      for (int j = 0; j < 4; ++j)                                                 \
        fb[j].q = *(const u32x4*)(&Bs[(BUF)][(brow + j * 16) * 32 + koff]);       \
      _Pragma("unroll")                                                           \
      for (int i = 0; i < 4; ++i)                                                 \
        _Pragma("unroll")                                                         \
        for (int j = 0; j < 4; ++j)                                               \
          acc[i][j] = __builtin_amdgcn_mfma_f32_16x16x32_bf16(fa[i].b, fb[j].b,   \
                                                              acc[i][j], 0, 0, 0);\
    } while (0)

  // ---- pipelined K-loop: 16 steps of BK=32, 2-buf / 1-deep prefetch ----
  STAGE(0, 0);
  #pragma unroll
  for (int ks = 0; ks < 15; ++ks) {
    STAGE((ks + 1) & 1, (ks + 1) * 32);                  // prefetch next (3 loads)
    asm volatile("s_waitcnt vmcnt(3)" ::: "memory");     // my stage(ks) landed
    __builtin_amdgcn_s_barrier();                        // everyone's landed
    asm volatile("" ::: "memory");
    COMPUTE(ks & 1);
    asm volatile("s_waitcnt lgkmcnt(0)" ::: "memory");   // my ds_reads done
    __builtin_amdgcn_sched_barrier(0);
    __builtin_amdgcn_s_barrier();                        // safe to overwrite buf
  }
  asm volatile("s_waitcnt vmcnt(0)" ::: "memory");
  __builtin_amdgcn_s_barrier();
  asm volatile("" ::: "memory");
  COMPUTE(1);                                            // step 15
  #undef STAGE
  #undef COMPUTE

  // ---- epilogue (cls aliases As[0]; all reads of As are complete) ----
  __syncthreads();
  for (int t = tid; t < 128 * NC; t += 512) cls[t] = 0.f;
  __syncthreads();

  const float beta = betap[0];
  const int mbase = mt * 256 + we * 64 + (lane & 15);
  int   lab[4]; float esq[4]; bool mv[4];
  #pragma unroll
  for (int j = 0; j < 4; ++j) {
    const int m = mbase + j * 16;
    mv[j]  = (m < M_TOT);
    esq[j] = e_sq[m];
    lab[j] = mv[j] ? labels[m] : 0;
  }

  #pragma unroll
  for (int i = 0; i < 4; ++i) {
    #pragma unroll
    for (int r = 0; r < 4; ++r) {
      const int nloc = wx * 64 + i * 16 + (lane >> 4) * 4 + r;  // C: row=(lane>>4)*4+reg
      const float xs = x_sq[nt * 128 + nloc];
      #pragma unroll
      for (int j = 0; j < 4; ++j) {
        if (!mv[j]) continue;
        const float dist = xs + esq[j] - 2.0f * acc[i][j][r];
        const float a = __expf(-beta * dist);
        if (a != 0.0f) atomicAdd(&cls[nloc * NC + lab[j]], a);  // adding 0 is identity
      }
    }
  }
  __syncthreads();
  for (int t = tid; t < 128 * NC; t += 512) {
    const float v = cls[t];
    if (v != 0.0f) atomicAdd(&logits[(size_t)(nt * 128 + (t / NC)) * NC + (t % NC)], v);
  }
}

// Output dtype is FLOAT32 (reference returns f32 softmax) — write float*.
__global__ void softmax_out(const float* __restrict__ logits,
                            const float* __restrict__ gammap,
                            float* __restrict__ out) {
  const int n = blockIdx.x * blockDim.x + threadIdx.x;
  if (n >= N_TOT) return;
  const float g = gammap[0];
  float v[NC], mx = -3.4e38f;
  #pragma unroll
  for (int c = 0; c < NC; ++c) { v[c] = g * logits[n * NC + c]; mx = fmaxf(mx, v[c]); }
  float s = 0.f;
  #pragma unroll
  for (int c = 0; c < NC; ++c) { v[c] = __expf(v[c] - mx); s += v[c]; }
  const float inv = 1.0f / s;
  #pragma unroll
  for (int c = 0; c < NC; ++c) out[n * NC + c] = v[c] * inv;
}

extern "C" void kernel_launch(void* const* d_in, const int* in_sizes, int n_in,
                              void* d_out, int out_size, void* d_ws, size_t ws_size,
                              hipStream_t stream) {
  const float* x      = (const float*)d_in[0];
  const float* e      = (const float*)d_in[1];
  const int*   labels = (const int*)d_in[2];
  const float* S      = (const float*)d_in[3];
  const float* beta   = (const float*)d_in[4];
  const float* gamma  = (const float*)d_in[5];

  char* ws = (char*)d_ws;
  unsigned short* eb     = (unsigned short*)(ws);              // 50176*512*2 = 51,380,224
  unsigned short* xb     = (unsigned short*)(ws + 51380224);   // 1024*512*2  =  1,048,576
  float*          e_sq   = (float*)(ws + 52428800);            // 50176*4     =    200,704
  float*          x_sq   = (float*)(ws + 52629504);            // 1024*4      =      4,096
  float*          logits = (float*)(ws + 52633600);            // 1024*10*4   =     40,960
  // total ws use: 52,674,560 bytes (~50.2 MiB)

  hipLaunchKernelGGL(prep_rows, dim3((M_PAD + N_TOT) / 4), dim3(256), 0, stream,
                     e, x, S, eb, xb, e_sq, x_sq, logits);
  hipLaunchKernelGGL(gemm_fused, dim3(8 * MT_TILES), dim3(512), 0, stream,
                     xb, eb, x_sq, e_sq, labels, beta, logits);
  hipLaunchKernelGGL(softmax_out, dim3(4), dim3(256), 0, stream,
                     logits, gamma, (float*)d_out);
}